// Round 4
// baseline (126.093 us; speedup 1.0000x reference)
//
#include <hip/hip_runtime.h>
#include <math.h>

#define HH 1024
#define WW 1024
#define OUTW 58            // output columns per wave (64 lanes - 6 halo)
#define RPB 4              // output rows per WAVE (vertical slide length)
#define WPB 4              // waves per block (independent y-strips, no barrier)
#define OFF(i) ((i)*8 - (i)*((i)-1)/2)   // packed upper-tri row offset

// ===== R20: R19 (DPP htap, 76 VGPR) + dual register prefetch =====
// Hard-won constraints (rounds 4..19):
//  - VGPR bucket MUST stay 128. WRITE_SIZE == 13536 KB is the no-spill
//    invariant (r7/r16: 40/39 MB; r17: 92 MB; r18: 43 MB).
//  - R19's fused-DPP prefix htap (6x v_add_f32_dpp, no bpermute) cut
//    VGPR 128 -> 76 and occupancy 16.6 -> 24.2%, dur flat at ~57 us:
//    per-wave issue density DROPPED to ~23% -> pure exposed-VMEM-latency
//    plateau. The prefetch idea (r17/r18) failed only on register
//    budget; the budget now exists (~50 regs of slack).
//  - Cross-lane ops (DPP) never inside divergent flow (r8).
//  - No LDS prefetch: s_waitcnt vmcnt(0) drains output stores (r15).
//  - TLP up/down and packed fp32 regressed (r10/r13/r16).
// R20 changes vs R19:
//  - Loop rotated (R17 structure): iter y consumes pre-loaded rows.
//    prefA (next add-row, HBM-cold) issues between AtA htaps and the
//    solve -> LDL^T serial chain is the VMEM shadow (~900 cy of cover).
//    prefS (next sub-row, L2-warm) issues between the solve and the
//    AtY taps (~450 cy of cover).
//  - Ledger: 76 + 22 prefetch floats ~= 100 < 128 bucket. Tripwire:
//    WRITE_SIZE must stay 13536 KB, else revert prefetch.

// DPP move, bound_ctrl=1 (invalid lanes read 0)
template<int CTRL>
__device__ __forceinline__ float dpp0(float x) {
    return __int_as_float(
        __builtin_amdgcn_update_dpp(0, __float_as_int(x), CTRL, 0xf, 0xf, true));
}
// whole-wave shift right by 1 lane (crosses 16-lane row boundaries)
__device__ __forceinline__ float wshr1(float x) { return dpp0<0x138>(x); }

// fp32 reciprocal: v_rcp_f32 + 1 Newton step (~1ulp); LDL^T is sqrt-free
__device__ __forceinline__ float frcp_fast(float s) {
    float r = __builtin_amdgcn_rcpf(s);
    return r * fmaf(-s, r, 2.0f);
}

__global__ __launch_bounds__(WPB * 64, 2) void ls_sep_kernel(
    const float* __restrict__ inp,    // [3,H,W]
    const float* __restrict__ dep,    // [1,H,W]
    const float* __restrict__ alb,    // [3,H,W]
    const float* __restrict__ nrm,    // [3,H,W]
    float* __restrict__ out)          // [3,H,W]
{
    const int L  = threadIdx.x & 63;          // lane 0..63
    const int wv = threadIdx.x >> 6;          // wave 0..3 (independent y-strip)
    const int HW = HH * WW;
    // lane L sums column x; its horizontal window (x-6..x) is centered at x-3
    const int x  = OUTW * blockIdx.x - 3 + L;
    const int y0 = (RPB * WPB) * blockIdx.y + RPB * wv;
    const int px = x - 3;                     // output pixel column for this lane

    const int xc    = min(max(x, 0), WW - 1);
    const float xok = (x >= 0 && x < WW) ? 1.f : 0.f;

    float C[60];                              // running column sums (7 rows in y)
    #pragma unroll
    for (int k = 0; k < 60; k++) C[k] = 0.f;

    // clamped-address loads only; no C update (prefetchable)
    auto load_row = [&](int yy, float (&fv)[8], float (&yv)[3]) {
        const int yc = min(max(yy, 0), HH - 1);
        const int p = yc * WW + xc;
        fv[0] = 1.f;
        fv[1] = dep[p];
        fv[2] = alb[p];
        fv[3] = alb[p + HW];
        fv[4] = alb[p + 2 * HW];
        fv[5] = nrm[p];
        fv[6] = nrm[p + HW];
        fv[7] = nrm[p + 2 * HW];
        yv[0] = inp[p];
        yv[1] = inp[p + HW];
        yv[2] = inp[p + 2 * HW];
    };

    // masked accumulate of a loaded row into the column sums
    auto apply_row = [&](const float (&fv)[8], const float (&yv)[3],
                         int yy, float sgn) {
        const float ok = (yy >= 0 && yy < HH) ? xok : 0.f;
        const float s = sgn * ok;
        float fs[8];
        #pragma unroll
        for (int i = 0; i < 8; i++) fs[i] = fv[i] * s;
        int k = 0;
        #pragma unroll
        for (int i = 0; i < 8; i++)
            #pragma unroll
            for (int j = i; j < 8; j++) { C[k] = fmaf(fs[i], fv[j], C[k]); k++; }
        #pragma unroll
        for (int i = 0; i < 8; i++)
            #pragma unroll
            for (int c = 0; c < 3; c++)
                C[36 + i * 3 + c] = fmaf(fs[i], yv[c], C[36 + i * 3 + c]);
    };

    // prologue prefetch of iter-y0's add-row: latency covered by preload
    float pAf[8], pAy[3];
    load_row(y0 + 3, pAf, pAy);

    // preload rows y0-3 .. y0+2 (iter y0 skips the subtract; window y0-3..y0+3)
    #pragma unroll 1
    for (int yy = y0 - 3; yy < y0 + 3; yy++) {
        float fv[8], yv[3];
        load_row(yy, fv, yv);
        apply_row(fv, yv, yy, 1.f);
    }

    float pSf[8], pSy[3];                     // first written in iter y0,
                                              // first read in iter y0+1

    const int pxc = min(max(px, 0), WW - 1);
    const bool do_store = (L >= 6) && (px < WW);

    // Batched horizontal 7-tap over lanes L-6..L for 12 values at once.
    // 6-step fused-DPP prefix chain: S_k covers lanes L-k..L; each
    // update_dpp result is single-use so it fuses into v_add_f32_dpp.
    // MUST be called by all 64 lanes (cross-lane inside).
    auto htap12 = [&](int base, float* dst) {
        #pragma unroll
        for (int j = 0; j < 12; j++) {
            const float xv = C[base + j];
            float S = xv;
            #pragma unroll
            for (int t = 0; t < 6; t++) S = xv + wshr1(S);
            dst[j] = S;
        }
    };

    #pragma unroll 1
    for (int y = y0; y < y0 + RPB; y++) {
        // ---- consume prefetched rows ----
        apply_row(pAf, pAy, y + 3, 1.f);
        if (y > y0) apply_row(pSf, pSy, y - 4, -1.f);   // wave-uniform branch

        // center-pixel features EARLY: L1/L2-hit latency hides under taps
        const int pc = y * WW + pxc;
        float cf[8];
        cf[0] = 1.f;
        cf[1] = dep[pc];
        cf[2] = alb[pc]; cf[3] = alb[pc + HW]; cf[4] = alb[pc + 2 * HW];
        cf[5] = nrm[pc]; cf[6] = nrm[pc + HW]; cf[7] = nrm[pc + 2 * HW];

        // ---- horizontal taps for AtA (AtY deferred past the solve) ----
        float W[36];
        htap12(0,  &W[0]);
        htap12(12, &W[12]);
        htap12(24, &W[24]);
        #pragma unroll
        for (int i = 0; i < 8; i++) W[OFF(i)] += 1.0e-4f;

        const bool more = (y + 1 < y0 + RPB);           // wave-uniform

        // prefetch next add-row (HBM-cold): latency hides under the solve
        if (more) load_row(y + 4, pAf, pAy);

        // ---- fp32 LDL^T (sqrt-free). W row i keeps R_ij = d_i*U_ij ----
        float idv[8];
        #pragma unroll
        for (int i = 0; i < 8; i++) {
            #pragma unroll
            for (int k = 0; k < i; k++) {
                const float c = W[OFF(k) + i - k] * idv[k];   // U_ki
                #pragma unroll
                for (int j = i; j < 8; j++)
                    W[OFF(i) + j - i] = fmaf(-c, W[OFF(k) + j - k], W[OFF(i) + j - i]);
            }
            idv[i] = frcp_fast(W[OFF(i)]);    // 1/d_i
        }

        // forward: vt_i = idv_i * (cf_i - sum_{k<i} R_ki * vt_k)
        float vt[8];
        #pragma unroll
        for (int i = 0; i < 8; i++) {
            float s = cf[i];
            #pragma unroll
            for (int k = 0; k < i; k++)
                s = fmaf(-W[OFF(k) + i - k], vt[k], s);
            vt[i] = s * idv[i];
        }
        // back: w_i = vt_i - idv_i * sum_{j>i} R_ij * w_j
        float w[8];
        #pragma unroll
        for (int i = 7; i >= 0; i--) {
            float t = 0.f;
            #pragma unroll
            for (int j = i + 1; j < 8; j++)
                t = fmaf(W[OFF(i) + j - i], w[j], t);
            w[i] = fmaf(-idv[i], t, vt[i]);
        }

        // prefetch next sub-row (L2-warm): latency hides under AtY taps + dots
        if (more) load_row(y - 3, pSf, pSy);

        // ---- deferred AtY taps (batched) + output dot products:
        //      ALL lanes execute; only the store is predicated ----
        float r[3] = {0.f, 0.f, 0.f};
        {
            float SY[12];
            htap12(36, SY);                   // AtY for i=0..3
            #pragma unroll
            for (int i = 0; i < 4; i++)
                #pragma unroll
                for (int c = 0; c < 3; c++)
                    r[c] = fmaf(w[i], SY[i * 3 + c], r[c]);
            htap12(48, SY);                   // AtY for i=4..7
            #pragma unroll
            for (int i = 0; i < 4; i++)
                #pragma unroll
                for (int c = 0; c < 3; c++)
                    r[c] = fmaf(w[i + 4], SY[i * 3 + c], r[c]);
        }

        if (do_store) {
            const int p = y * WW + px;
            #pragma unroll
            for (int c = 0; c < 3; c++)
                out[c * HW + p] = r[c];
        }
    }
}

extern "C" void kernel_launch(void* const* d_in, const int* in_sizes, int n_in,
                              void* d_out, int out_size, void* d_ws, size_t ws_size,
                              hipStream_t stream) {
    const float* inp = (const float*)d_in[0];
    const float* dep = (const float*)d_in[1];
    const float* alb = (const float*)d_in[2];
    const float* nrm = (const float*)d_in[3];
    float* out = (float*)d_out;
    dim3 grid((WW + OUTW - 1) / OUTW, HH / (RPB * WPB));   // 18 x 64, 256-thr blocks
    ls_sep_kernel<<<grid, dim3(WPB * 64), 0, stream>>>(inp, dep, alb, nrm, out);
}